// Round 13
// baseline (18.301 us; speedup 1.0000x reference)
//
#include <hip/hip_runtime.h>
#include <math.h>

// Problem constants (from reference setup_inputs)
#define B 8
#define S 512
#define G 16
#define DA 1024
#define DM 256
#define WIN 12
#define DTOT (DA + DM)            // 1280 pooled dims
#define NW 8                      // waves per block (512 threads)
#define NWIN (B * (G - 1))        // 120 window blocks (g>=1)
#define NSL 20                    // 64-wide d-slices (16 att + 4 mod)
#define NSCAN (B * NSL)           // 160 g0 scan blocks (placed FIRST)
#define NBLK (NSCAN + NWIN + B)   // + 8 center blocks = 288 total

__inline__ __device__ float4 fmax4(float4 a, float4 b) {
    return make_float4(fmaxf(a.x, b.x), fmaxf(a.y, b.y),
                       fmaxf(a.z, b.z), fmaxf(a.w, b.w));
}
__inline__ __device__ float4 add4(float4 a, float4 b) {
    return make_float4(a.x + b.x, a.y + b.y, a.z + b.z, a.w + b.w);
}
__inline__ __device__ float dot4(float4 a, float4 b) {
    return a.x * b.x + a.y * b.y + a.z * b.z + a.w * b.w;
}

// 8-wave (512-thread) batched block reduce: 4 sums in one LDS round.
__inline__ __device__ float4 blockReduceSum4_8(float4 v, float4* sh) {
    int lane = threadIdx.x & 63, w = threadIdx.x >> 6;
#pragma unroll
    for (int o = 32; o > 0; o >>= 1) {
        v.x += __shfl_xor(v.x, o, 64);
        v.y += __shfl_xor(v.y, o, 64);
        v.z += __shfl_xor(v.z, o, 64);
        v.w += __shfl_xor(v.w, o, 64);
    }
    __syncthreads();
    if (lane == 0) sh[w] = v;
    __syncthreads();
    float4 r = sh[0];
#pragma unroll
    for (int ww = 1; ww < 8; ++ww) {
        r.x += sh[ww].x; r.y += sh[ww].y; r.z += sh[ww].z; r.w += sh[ww].w;
    }
    return r;
}

// ONE worker kernel, 288 independent blocks (no partials, no fences):
//  bid < NSCAN:           g0 d-slice scan  -> atomicAdd into out[b,0]
//  bid < NSCAN+NWIN:      window logit g>=1 -> plain store to out[b,g]
//  else (8 blocks):       g0 center dot + biases -> atomicAdd into out[b,0]
// Scans first: they stream 128 KB each (the long pole) and must start early;
// the light window blocks absorb the >256-block scheduling tail.
__global__ __launch_bounds__(512) void k_main(
    const float* __restrict__ att, const float* __restrict__ mod,
    const float* __restrict__ Wa, const float* __restrict__ Wm,
    const float* __restrict__ ba, const float* __restrict__ bm,
    const int* __restrict__ gidx, const int* __restrict__ mask,
    float* __restrict__ out)
{
    __shared__ float part[NW][DTOT];   // 40 KB (windows); scans alias 1 KB
    __shared__ float4 s4[NW];
    const int bid = blockIdx.x;
    const int t = threadIdx.x, lane = t & 63, w = t >> 6;

    const float4* att4 = (const float4*)att;
    const float4* mod4 = (const float4*)mod;

    if (bid < NSCAN) {
        // ---------------- g0 d-slice scan (independent, raw reads) --------
        const int b = bid / NSL, c = bid % NSL;

        // Issue the mask load now; reduce it AFTER the heavy loop.
        float cmv = (float)mask[b * S + t];

        // Wave w scans rows s = w, w+8, ...; lane owns d = c*64+lane.
        // g0 max is UNMASKED (reference: jnp.max(x, axis=1)); sum over all
        // rows. Two accumulators (even/odd) double the VALU ILP.
        float mx0 = -INFINITY, mx1 = -INFINITY, sm0 = 0.f, sm1 = 0.f;
        if (c < 16) {
            const float* base = att + (size_t)b * S * DA + c * 64 + lane;
#pragma unroll 4
            for (int s = w; s < S; s += 2 * NW) {
                float v0 = base[(size_t)s * DA];
                float v1 = base[(size_t)(s + NW) * DA];
                mx0 = fmaxf(mx0, v0);  sm0 += v0;
                mx1 = fmaxf(mx1, v1);  sm1 += v1;
            }
        } else {
            const float* base = mod + (size_t)b * S * DM + (c - 16) * 64 + lane;
#pragma unroll 4
            for (int s = w; s < S; s += 2 * NW) {
                float v0 = base[(size_t)s * DM];
                float v1 = base[(size_t)(s + NW) * DM];
                mx0 = fmaxf(mx0, v0);  sm0 += v0;
                mx1 = fmaxf(mx1, v1);  sm1 += v1;
            }
        }
        float mx = fmaxf(mx0, mx1), sm = sm0 + sm1;

        // cm reduce (now that the loads are issued/consumed).
        float cm = blockReduceSum4_8(make_float4(cmv, 0.f, 0.f, 0.f), s4).x;

        // Cross-wave merge through 1 KB of the part buffer.
        float* pMf = &part[0][0];     // 8*64 floats
        float* pSf = &part[0][512];   // 8*64 floats
        pMf[w * 64 + lane] = mx;
        pSf[w * 64 + lane] = sm;
        __syncthreads();

        if (t < 64) {
            float m2 = pMf[t], s2 = pSf[t];
#pragma unroll
            for (int ww = 1; ww < NW; ++ww) {
                m2 = fmaxf(m2, pMf[ww * 64 + t]);
                s2 += pSf[ww * 64 + t];
            }
            const int d2 = c * 64 + t;
            float w1 = (d2 < DA) ? Wa[DA + d2] : Wm[DM + (d2 - DA)];
            float w2 = (d2 < DA) ? Wa[2 * DA + d2] : Wm[2 * DM + (d2 - DA)];
            float val = w1 * m2 + w2 * (s2 / cm);
#pragma unroll
            for (int o = 32; o > 0; o >>= 1) val += __shfl_xor(val, o, 64);
            if (t == 0) atomicAdd(&out[b * G], val);
        }
    } else if (bid < NSCAN + NWIN) {
        // ---------------- window logit g>=1 (verified R9-R12 path) --------
        const int idx = bid - NSCAN;
        const int b = idx / (G - 1), g = 1 + idx % (G - 1);
        const int gi = gidx[b * G + g];

        // Center-row gather dot: att[gi]·W0a + mod[gi]·W0m.
        float cd = 0.f;
        if (t < 256)
            cd = dot4(att4[(size_t)(b * S + gi) * (DA / 4) + t],
                      ((const float4*)Wa)[t]);
        else if (t < 256 + DM / 4)
            cd = dot4(mod4[(size_t)(b * S + gi) * (DM / 4) + (t - 256)],
                      ((const float4*)Wm)[t - 256]);

        int lo = gi - WIN; if (lo < 0) lo = 0;
        int hi = gi + WIN; if (hi > S - 1) hi = S - 1;

        // Per-d windowed masked max (clamped at 0 by the reference's x*wmf
        // form; window <= 25 < 512 rows always leaves zeros) and masked sum.
        float4 amax2[4], asum2[4];
#pragma unroll
        for (int k = 0; k < 4; ++k) {
            amax2[k] = make_float4(0.f, 0.f, 0.f, 0.f);
            asum2[k] = make_float4(0.f, 0.f, 0.f, 0.f);
        }
        float4 mmax2 = make_float4(0.f, 0.f, 0.f, 0.f);
        float4 msum2 = make_float4(0.f, 0.f, 0.f, 0.f);
        float cn = 0.f;

        for (int s = lo + w; s <= hi; s += NW) {
            if (mask[b * S + s] > 0) {
                const int row = b * S + s;
                const float4* arow = att4 + (size_t)row * (DA / 4);
#pragma unroll
                for (int k = 0; k < 4; ++k) {
                    float4 v = arow[lane + 64 * k];
                    amax2[k] = fmax4(amax2[k], v);
                    asum2[k] = add4(asum2[k], v);
                }
                float4 vm = mod4[(size_t)row * (DM / 4) + lane];
                mmax2 = fmax4(mmax2, vm);
                msum2 = add4(msum2, vm);
                if (lane == 0) cn += 1.f;
            }
        }

        float4* pr = (float4*)&part[w][0];

        // Pass 1: merge maxes, dot with max-slice weights.
#pragma unroll
        for (int k = 0; k < 4; ++k) pr[lane + 64 * k] = amax2[k];
        ((float4*)&part[w][DA])[lane] = mmax2;
        __syncthreads();
        float wdot1 = 0.f;
        for (int d = t; d < DTOT; d += 512) {
            float mx = part[0][d];
#pragma unroll
            for (int ww = 1; ww < 8; ++ww) mx = fmaxf(mx, part[ww][d]);
            float wgt = (d < DA) ? Wa[DA + d] : Wm[DM + (d - DA)];
            wdot1 += wgt * mx;
        }
        __syncthreads();

        // Pass 2: merge sums, dot with avg-slice weights.
#pragma unroll
        for (int k = 0; k < 4; ++k) pr[lane + 64 * k] = asum2[k];
        ((float4*)&part[w][DA])[lane] = msum2;
        __syncthreads();
        float wdot2 = 0.f;
        for (int d = t; d < DTOT; d += 512) {
            float sm = part[0][d];
#pragma unroll
            for (int ww = 1; ww < 8; ++ww) sm += part[ww][d];
            float wgt = (d < DA) ? Wa[2 * DA + d] : Wm[2 * DM + (d - DA)];
            wdot2 += wgt * sm;
        }

        float4 r = blockReduceSum4_8(make_float4(wdot1, wdot2, cd, cn), s4);
        if (t == 0)
            out[b * G + g] = r.z + r.x + r.y / r.w + ba[0] + bm[0];
    } else {
        // ---------------- g0 center dot + biases --------------------------
        const int b = bid - NSCAN - NWIN;
        const int gi = gidx[b * G];
        float cd = 0.f;
        if (t < 256)
            cd = dot4(att4[(size_t)(b * S + gi) * (DA / 4) + t],
                      ((const float4*)Wa)[t]);
        else if (t < 256 + DM / 4)
            cd = dot4(mod4[(size_t)(b * S + gi) * (DM / 4) + (t - 256)],
                      ((const float4*)Wm)[t - 256]);
        float4 r = blockReduceSum4_8(make_float4(cd, 0.f, 0.f, 0.f), s4);
        if (t == 0) atomicAdd(&out[b * G], r.x + ba[0] + bm[0]);
    }
}

extern "C" void kernel_launch(void* const* d_in, const int* in_sizes, int n_in,
                              void* d_out, int out_size, void* d_ws, size_t ws_size,
                              hipStream_t stream) {
    const float* att  = (const float*)d_in[0];
    const float* mod  = (const float*)d_in[1];
    const float* Wa   = (const float*)d_in[2];
    const float* ba   = (const float*)d_in[3];
    const float* Wm   = (const float*)d_in[4];
    const float* bm   = (const float*)d_in[5];
    // d_in[6] = q_enc (unused by reference)
    const int* gidx   = (const int*)d_in[7];
    const int* mask   = (const int*)d_in[8];
    // d_in[9] = q_mask (unused by reference)
    float* out = (float*)d_out;

    // g0 accumulates via atomicAdd -> out must be zeroed every replay.
    hipMemsetAsync(out, 0, (size_t)out_size * sizeof(float), stream);
    k_main<<<NBLK, 512, 0, stream>>>(att, mod, Wa, Wm, ba, bm, gidx, mask, out);
}